// Round 1
// baseline (1597.204 us; speedup 1.0000x reference)
//
#include <hip/hip_runtime.h>

#define NN 100000
#define NE 1600000
#define FD 64
#define NG 128

// ---------------- degree / normalization ----------------
__global__ void deg_init_k(float* deg) {
    int n = blockIdx.x * blockDim.x + threadIdx.x;
    if (n < NN) deg[n] = 1.0f;  // self-loop
}

__global__ void deg_count_k(const int* __restrict__ dst, float* deg) {
    int e = blockIdx.x * blockDim.x + threadIdx.x;
    if (e < NE) atomicAdd(&deg[dst[e]], 1.0f);
}

__global__ void deg_rsqrt_k(float* deg) {
    int n = blockIdx.x * blockDim.x + threadIdx.x;
    if (n < NN) deg[n] = rsqrtf(deg[n]);  // deg -> dis in place
}

// ---------------- GEMM: out[N,64] = act(h)[N,64] @ W[64,64] ----------------
// 32 rows per block, 256 threads. W staged in LDS (16KB), h rows in LDS (8KB).
template <bool RELU_IN>
__global__ void gemm64_k(const float* __restrict__ h, const float* __restrict__ W,
                         float* __restrict__ out) {
    __shared__ float wS[64 * 64];
    __shared__ float hS[32 * 64];
    int tid = threadIdx.x;
    int rbase = blockIdx.x * 32;

#pragma unroll
    for (int i = 0; i < 16; i++) wS[tid + i * 256] = W[tid + i * 256];
#pragma unroll
    for (int i = 0; i < 8; i++) {
        int idx = tid + i * 256;           // 0..2047
        int r = rbase + (idx >> 6);
        float v = (r < NN) ? h[r * FD + (idx & 63)] : 0.0f;
        if (RELU_IN) v = fmaxf(v, 0.0f);
        hS[idx] = v;
    }
    __syncthreads();

    int col = tid & 63, rg = tid >> 6;
    float acc[8];
#pragma unroll
    for (int i = 0; i < 8; i++) acc[i] = 0.0f;

    for (int k = 0; k < 64; k++) {
        float w = wS[k * 64 + col];
#pragma unroll
        for (int i = 0; i < 8; i++)
            acc[i] = fmaf(hS[(rg * 8 + i) * 64 + k], w, acc[i]);
    }
#pragma unroll
    for (int i = 0; i < 8; i++) {
        int r = rbase + rg * 8 + i;
        if (r < NN) out[r * FD + col] = acc[i];
    }
}

// ---------------- agg init: agg = b + dis^2 * h2 (self-loop term) ----------------
__global__ void agg_init_k(const float* __restrict__ h2, const float* __restrict__ dis,
                           const float* __restrict__ b, float* __restrict__ agg) {
    int i = blockIdx.x * blockDim.x + threadIdx.x;
    if (i < NN * FD) {
        int n = i >> 6, f = i & 63;
        float d = dis[n];
        agg[i] = b[f] + d * d * h2[i];
    }
}

// ---------------- edge scatter: one wave per edge ----------------
__global__ void scatter_k(const float* __restrict__ h2, const int* __restrict__ src,
                          const int* __restrict__ dst, const float* __restrict__ dis,
                          float* __restrict__ agg) {
    int widx = (blockIdx.x * blockDim.x + threadIdx.x) >> 6;
    int lane = threadIdx.x & 63;
    if (widx >= NE) return;
    int s = src[widx];
    int d = dst[widx];
    float w = dis[s] * dis[d];
    atomicAdd(&agg[d * FD + lane], w * h2[s * FD + lane]);
}

// ---------------- pooling: per-wave running sum, flush on graph change ----------------
__global__ void pool_acc_k(const float* __restrict__ h, const int* __restrict__ batch,
                           float* __restrict__ pool) {
    int wid = (blockIdx.x * blockDim.x + threadIdx.x) >> 6;
    int lane = threadIdx.x & 63;
    int n0 = wid * 32;
    if (n0 >= NN) return;
    int n1 = min(n0 + 32, NN);
    int g = batch[n0];
    float acc = 0.0f;
    for (int n = n0; n < n1; n++) {
        int gn = batch[n];
        if (gn != g) {
            atomicAdd(&pool[g * FD + lane], acc);
            acc = 0.0f;
            g = gn;
        }
        acc += h[n * FD + lane];
    }
    atomicAdd(&pool[g * FD + lane], acc);
}

// ---------------- counts via binary search on sorted batch ----------------
__global__ void cnt_k(const int* __restrict__ batch, float* __restrict__ cnt) {
    int g = threadIdx.x;
    if (g >= NG) return;
    auto lb = [&](int key) {
        int lo = 0, hi = NN;
        while (lo < hi) {
            int mid = (lo + hi) >> 1;
            if (batch[mid] < key) lo = mid + 1; else hi = mid;
        }
        return lo;
    };
    cnt[g] = (float)(lb(g + 1) - lb(g));
}

// ---------------- final: out[g] = (pool[g] . lin_w) / cnt[g] + lin_b ----------------
__global__ void final_k(const float* __restrict__ pool, const float* __restrict__ cnt,
                        const float* __restrict__ lin_w, const float* __restrict__ lin_b,
                        float* __restrict__ out) {
    int g = blockIdx.x * blockDim.x + threadIdx.x;
    if (g >= NG) return;
    float c = fmaxf(cnt[g], 1.0f);
    float s = 0.0f;
    for (int f = 0; f < FD; f++) s += pool[g * FD + f] * lin_w[f];
    out[g] = s / c + lin_b[0];
}

extern "C" void kernel_launch(void* const* d_in, const int* in_sizes, int n_in,
                              void* d_out, int out_size, void* d_ws, size_t ws_size,
                              hipStream_t stream) {
    const float* x      = (const float*)d_in[0];
    const int*   src    = (const int*)d_in[1];          // edge_index[0]
    const int*   dst    = ((const int*)d_in[1]) + NE;   // edge_index[1]
    const int*   batch  = (const int*)d_in[2];
    const float* W1 = (const float*)d_in[3];  const float* b1 = (const float*)d_in[4];
    const float* W2 = (const float*)d_in[5];  const float* b2 = (const float*)d_in[6];
    const float* W3 = (const float*)d_in[7];  const float* b3 = (const float*)d_in[8];
    const float* W4 = (const float*)d_in[9];  const float* b4 = (const float*)d_in[10];
    const float* lin_w = (const float*)d_in[11];
    const float* lin_b = (const float*)d_in[12];
    float* out = (float*)d_out;

    // workspace layout (floats)
    float* ws   = (float*)d_ws;
    float* dis  = ws;                       // NN
    float* tmp  = dis + NN;                 // NN*FD
    float* bufA = tmp + (size_t)NN * FD;    // NN*FD
    float* bufB = bufA + (size_t)NN * FD;   // NN*FD
    float* pool = bufB + (size_t)NN * FD;   // NG*FD
    float* cnt  = pool + NG * FD;           // NG

    // normalization
    deg_init_k<<<(NN + 255) / 256, 256, 0, stream>>>(dis);
    deg_count_k<<<(NE + 255) / 256, 256, 0, stream>>>(dst, dis);
    deg_rsqrt_k<<<(NN + 255) / 256, 256, 0, stream>>>(dis);

    const int GEMM_GRID = (NN + 31) / 32;
    const int ELT_GRID  = (NN * FD + 255) / 256;
    const int EDGE_GRID = (NE * 64 + 255) / 256;

    // layer 1: x -> bufA
    gemm64_k<false><<<GEMM_GRID, 256, 0, stream>>>(x, W1, tmp);
    agg_init_k<<<ELT_GRID, 256, 0, stream>>>(tmp, dis, b1, bufA);
    scatter_k<<<EDGE_GRID, 256, 0, stream>>>(tmp, src, dst, dis, bufA);

    // layer 2: relu(bufA) -> bufB
    gemm64_k<true><<<GEMM_GRID, 256, 0, stream>>>(bufA, W2, tmp);
    agg_init_k<<<ELT_GRID, 256, 0, stream>>>(tmp, dis, b2, bufB);
    scatter_k<<<EDGE_GRID, 256, 0, stream>>>(tmp, src, dst, dis, bufB);

    // layer 3: relu(bufB) -> bufA
    gemm64_k<true><<<GEMM_GRID, 256, 0, stream>>>(bufB, W3, tmp);
    agg_init_k<<<ELT_GRID, 256, 0, stream>>>(tmp, dis, b3, bufA);
    scatter_k<<<EDGE_GRID, 256, 0, stream>>>(tmp, src, dst, dis, bufA);

    // layer 4: relu(bufA) -> bufB (no relu on output)
    gemm64_k<true><<<GEMM_GRID, 256, 0, stream>>>(bufA, W4, tmp);
    agg_init_k<<<ELT_GRID, 256, 0, stream>>>(tmp, dis, b4, bufB);
    scatter_k<<<EDGE_GRID, 256, 0, stream>>>(tmp, src, dst, dis, bufB);

    // pooling + final linear
    hipMemsetAsync(pool, 0, NG * FD * sizeof(float), stream);
    pool_acc_k<<<((NN + 31) / 32 * 64 + 255) / 256, 256, 0, stream>>>(bufB, batch, pool);
    cnt_k<<<1, 128, 0, stream>>>(batch, cnt);
    final_k<<<1, 128, 0, stream>>>(pool, cnt, lin_w, lin_b, out);
}

// Round 2
// 697.951 us; speedup vs baseline: 2.2884x; 2.2884x over previous
//
#include <hip/hip_runtime.h>

#define NN 100000
#define NE 1600000
#define FD 64
#define NG 128
#define SCAN_CHUNK 1024
#define NCHUNK ((NN + SCAN_CHUNK - 1) / SCAN_CHUNK)   // 98

// ---------------- degree count (int) ----------------
__global__ void deg_count_k(const int* __restrict__ dst, int* __restrict__ degi) {
    int e = blockIdx.x * blockDim.x + threadIdx.x;
    if (e < NE) atomicAdd(&degi[dst[e]], 1);
}

__global__ void dis_k(const int* __restrict__ degi, float* __restrict__ dis) {
    int n = blockIdx.x * blockDim.x + threadIdx.x;
    if (n < NN) dis[n] = rsqrtf((float)degi[n] + 1.0f);  // +1 self-loop
}

// ---------------- exclusive scan (3 phases) ----------------
__global__ void scan1_k(const int* __restrict__ cnt, int* __restrict__ rowptr,
                        int* __restrict__ partial) {
    __shared__ int sS[256];
    int t = threadIdx.x;
    int base = blockIdx.x * SCAN_CHUNK + t * 4;
    int v[4], s = 0;
#pragma unroll
    for (int i = 0; i < 4; i++) {
        int idx = base + i;
        v[i] = (idx < NN) ? cnt[idx] : 0;
        s += v[i];
    }
    sS[t] = s;
    __syncthreads();
    for (int off = 1; off < 256; off <<= 1) {
        int x = (t >= off) ? sS[t - off] : 0;
        __syncthreads();
        if (t >= off) sS[t] += x;
        __syncthreads();
    }
    int run = (t == 0) ? 0 : sS[t - 1];
    if (t == 255) partial[blockIdx.x] = sS[255];
#pragma unroll
    for (int i = 0; i < 4; i++) {
        int idx = base + i;
        if (idx < NN) rowptr[idx] = run;
        run += v[i];
    }
}

__global__ void scan2_k(int* __restrict__ partial) {
    __shared__ int sS[256];
    int t = threadIdx.x;
    sS[t] = (t < NCHUNK) ? partial[t] : 0;
    __syncthreads();
    for (int off = 1; off < 256; off <<= 1) {
        int x = (t >= off) ? sS[t - off] : 0;
        __syncthreads();
        if (t >= off) sS[t] += x;
        __syncthreads();
    }
    if (t < NCHUNK) partial[t] = (t == 0) ? 0 : sS[t - 1];
}

__global__ void scan3_k(int* __restrict__ rowptr, const int* __restrict__ partial) {
    int i = blockIdx.x * blockDim.x + threadIdx.x;
    if (i < NN) rowptr[i] += partial[i >> 10];
    if (i == 0) rowptr[NN] = NE;
}

// ---------------- CSR fill: entries[rowptr[d]+pos] = {src, norm} ----------------
__global__ void fill_k(const int* __restrict__ src, const int* __restrict__ dst,
                       const float* __restrict__ dis, const int* __restrict__ rowptr,
                       int* __restrict__ cursor, int2* __restrict__ entries) {
    int e = blockIdx.x * blockDim.x + threadIdx.x;
    if (e >= NE) return;
    int s = src[e], d = dst[e];
    int pos = atomicAdd(&cursor[d], 1);
    entries[rowptr[d] + pos] = make_int2(s, __float_as_int(dis[s] * dis[d]));
}

// ---------------- GEMM: out[N,64] = act(h)[N,64] @ W[64,64] ----------------
template <bool RELU_IN>
__global__ void gemm64_k(const float* __restrict__ h, const float* __restrict__ W,
                         float* __restrict__ out) {
    __shared__ float wS[64 * 64];
    __shared__ float hS[32 * 64];
    int tid = threadIdx.x;
    int rbase = blockIdx.x * 32;

#pragma unroll
    for (int i = 0; i < 16; i++) wS[tid + i * 256] = W[tid + i * 256];
#pragma unroll
    for (int i = 0; i < 8; i++) {
        int idx = tid + i * 256;
        int r = rbase + (idx >> 6);
        float v = (r < NN) ? h[r * FD + (idx & 63)] : 0.0f;
        if (RELU_IN) v = fmaxf(v, 0.0f);
        hS[idx] = v;
    }
    __syncthreads();

    int col = tid & 63, rg = tid >> 6;
    float acc[8];
#pragma unroll
    for (int i = 0; i < 8; i++) acc[i] = 0.0f;

    for (int k = 0; k < 64; k++) {
        float w = wS[k * 64 + col];
#pragma unroll
        for (int i = 0; i < 8; i++)
            acc[i] = fmaf(hS[(rg * 8 + i) * 64 + k], w, acc[i]);
    }
#pragma unroll
    for (int i = 0; i < 8; i++) {
        int r = rbase + rg * 8 + i;
        if (r < NN) out[r * FD + col] = acc[i];
    }
}

// ---------------- gather: agg[n] = b + dis[n]^2*h2[n] + sum_in norm*h2[src] ----------------
__global__ void gather_k(const float* __restrict__ h2, const int* __restrict__ rowptr,
                         const int2* __restrict__ entries, const float* __restrict__ dis,
                         const float* __restrict__ b, float* __restrict__ agg) {
    int n = (blockIdx.x * blockDim.x + threadIdx.x) >> 6;
    int lane = threadIdx.x & 63;
    if (n >= NN) return;
    int e0 = rowptr[n], e1 = rowptr[n + 1];
    float d = dis[n];
    float acc = b[lane] + d * d * h2[n * FD + lane];
    int e = e0;
    for (; e + 1 < e1; e += 2) {
        int2 ea = entries[e];
        int2 eb = entries[e + 1];
        float va = h2[ea.x * FD + lane];
        float vb = h2[eb.x * FD + lane];
        acc += __int_as_float(ea.y) * va + __int_as_float(eb.y) * vb;
    }
    if (e < e1) {
        int2 ea = entries[e];
        acc += __int_as_float(ea.y) * h2[ea.x * FD + lane];
    }
    agg[n * FD + lane] = acc;
}

// ---------------- pooling ----------------
__global__ void pool_acc_k(const float* __restrict__ h, const int* __restrict__ batch,
                           float* __restrict__ pool) {
    int wid = (blockIdx.x * blockDim.x + threadIdx.x) >> 6;
    int lane = threadIdx.x & 63;
    int n0 = wid * 32;
    if (n0 >= NN) return;
    int n1 = min(n0 + 32, NN);
    int g = batch[n0];
    float acc = 0.0f;
    for (int n = n0; n < n1; n++) {
        int gn = batch[n];
        if (gn != g) {
            atomicAdd(&pool[g * FD + lane], acc);
            acc = 0.0f;
            g = gn;
        }
        acc += h[n * FD + lane];
    }
    atomicAdd(&pool[g * FD + lane], acc);
}

__global__ void cnt_k(const int* __restrict__ batch, float* __restrict__ cnt) {
    int g = threadIdx.x;
    if (g >= NG) return;
    auto lb = [&](int key) {
        int lo = 0, hi = NN;
        while (lo < hi) {
            int mid = (lo + hi) >> 1;
            if (batch[mid] < key) lo = mid + 1; else hi = mid;
        }
        return lo;
    };
    cnt[g] = (float)(lb(g + 1) - lb(g));
}

__global__ void final_k(const float* __restrict__ pool, const float* __restrict__ cnt,
                        const float* __restrict__ lin_w, const float* __restrict__ lin_b,
                        float* __restrict__ out) {
    int g = blockIdx.x * blockDim.x + threadIdx.x;
    if (g >= NG) return;
    float c = fmaxf(cnt[g], 1.0f);
    float s = 0.0f;
    for (int f = 0; f < FD; f++) s += pool[g * FD + f] * lin_w[f];
    out[g] = s / c + lin_b[0];
}

extern "C" void kernel_launch(void* const* d_in, const int* in_sizes, int n_in,
                              void* d_out, int out_size, void* d_ws, size_t ws_size,
                              hipStream_t stream) {
    const float* x     = (const float*)d_in[0];
    const int*   src   = (const int*)d_in[1];
    const int*   dst   = ((const int*)d_in[1]) + NE;
    const int*   batch = (const int*)d_in[2];
    const float* W1 = (const float*)d_in[3];  const float* b1 = (const float*)d_in[4];
    const float* W2 = (const float*)d_in[5];  const float* b2 = (const float*)d_in[6];
    const float* W3 = (const float*)d_in[7];  const float* b3 = (const float*)d_in[8];
    const float* W4 = (const float*)d_in[9];  const float* b4 = (const float*)d_in[10];
    const float* lin_w = (const float*)d_in[11];
    const float* lin_b = (const float*)d_in[12];
    float* out = (float*)d_out;

    // workspace layout
    char* p = (char*)d_ws;
    float* dis    = (float*)p;            p += (size_t)NN * 4;
    int*   degi   = (int*)p;              p += (size_t)NN * 4;
    int*   rowptr = (int*)p;              p += (size_t)(NN + 4) * 4;
    int*   cursor = (int*)p;              p += (size_t)NN * 4;
    int*   partial= (int*)p;              p += 256 * 4;
    int2*  entries= (int2*)p;             p += (size_t)NE * 8;
    float* tmp    = (float*)p;            p += (size_t)NN * FD * 4;
    float* bufA   = (float*)p;            p += (size_t)NN * FD * 4;
    float* pool   = (float*)p;            p += (size_t)NG * FD * 4;
    float* cnt    = (float*)p;            p += (size_t)NG * 4;

    const int NODE_GRID = (NN + 255) / 256;
    const int EDGE_GRID = (NE + 255) / 256;

    // ---- CSR build ----
    hipMemsetAsync(degi, 0, (size_t)NN * 4, stream);
    hipMemsetAsync(cursor, 0, (size_t)NN * 4, stream);
    deg_count_k<<<EDGE_GRID, 256, 0, stream>>>(dst, degi);
    dis_k<<<NODE_GRID, 256, 0, stream>>>(degi, dis);
    scan1_k<<<NCHUNK, 256, 0, stream>>>(degi, rowptr, partial);
    scan2_k<<<1, 256, 0, stream>>>(partial);
    scan3_k<<<NODE_GRID, 256, 0, stream>>>(rowptr, partial);
    fill_k<<<EDGE_GRID, 256, 0, stream>>>(src, dst, dis, rowptr, cursor, entries);

    const int GEMM_GRID = (NN + 31) / 32;
    const int WAVE_GRID = ((size_t)NN * 64 + 255) / 256;

    // layer 1: x -> bufA
    gemm64_k<false><<<GEMM_GRID, 256, 0, stream>>>(x, W1, tmp);
    gather_k<<<WAVE_GRID, 256, 0, stream>>>(tmp, rowptr, entries, dis, b1, bufA);
    // layer 2
    gemm64_k<true><<<GEMM_GRID, 256, 0, stream>>>(bufA, W2, tmp);
    gather_k<<<WAVE_GRID, 256, 0, stream>>>(tmp, rowptr, entries, dis, b2, bufA);
    // layer 3
    gemm64_k<true><<<GEMM_GRID, 256, 0, stream>>>(bufA, W3, tmp);
    gather_k<<<WAVE_GRID, 256, 0, stream>>>(tmp, rowptr, entries, dis, b3, bufA);
    // layer 4
    gemm64_k<true><<<GEMM_GRID, 256, 0, stream>>>(bufA, W4, tmp);
    gather_k<<<WAVE_GRID, 256, 0, stream>>>(tmp, rowptr, entries, dis, b4, bufA);

    // pooling + final
    hipMemsetAsync(pool, 0, (size_t)NG * FD * 4, stream);
    pool_acc_k<<<((NN + 31) / 32 * 64 + 255) / 256, 256, 0, stream>>>(bufA, batch, pool);
    cnt_k<<<1, 128, 0, stream>>>(batch, cnt);
    final_k<<<1, 128, 0, stream>>>(pool, cnt, lin_w, lin_b, out);
}

// Round 3
// 544.634 us; speedup vs baseline: 2.9326x; 1.2815x over previous
//
#include <hip/hip_runtime.h>
#include <hip/hip_fp16.h>

#define NN 100000
#define NE 1600000
#define FD 64
#define NG 128
#define SCAN_CHUNK 1024
#define NCHUNK ((NN + SCAN_CHUNK - 1) / SCAN_CHUNK)   // 98

// ---------------- degree count (int) ----------------
__global__ void deg_count_k(const int* __restrict__ dst, int* __restrict__ degi) {
    int e = blockIdx.x * blockDim.x + threadIdx.x;
    if (e < NE) atomicAdd(&degi[dst[e]], 1);
}

__global__ void dis_k(const int* __restrict__ degi, float* __restrict__ dis) {
    int n = blockIdx.x * blockDim.x + threadIdx.x;
    if (n < NN) dis[n] = rsqrtf((float)degi[n] + 1.0f);  // +1 self-loop
}

// ---------------- exclusive scan (3 phases) ----------------
__global__ void scan1_k(const int* __restrict__ cnt, int* __restrict__ rowptr,
                        int* __restrict__ partial) {
    __shared__ int sS[256];
    int t = threadIdx.x;
    int base = blockIdx.x * SCAN_CHUNK + t * 4;
    int v[4], s = 0;
#pragma unroll
    for (int i = 0; i < 4; i++) {
        int idx = base + i;
        v[i] = (idx < NN) ? cnt[idx] : 0;
        s += v[i];
    }
    sS[t] = s;
    __syncthreads();
    for (int off = 1; off < 256; off <<= 1) {
        int x = (t >= off) ? sS[t - off] : 0;
        __syncthreads();
        if (t >= off) sS[t] += x;
        __syncthreads();
    }
    int run = (t == 0) ? 0 : sS[t - 1];
    if (t == 255) partial[blockIdx.x] = sS[255];
#pragma unroll
    for (int i = 0; i < 4; i++) {
        int idx = base + i;
        if (idx < NN) rowptr[idx] = run;
        run += v[i];
    }
}

__global__ void scan2_k(int* __restrict__ partial) {
    __shared__ int sS[256];
    int t = threadIdx.x;
    sS[t] = (t < NCHUNK) ? partial[t] : 0;
    __syncthreads();
    for (int off = 1; off < 256; off <<= 1) {
        int x = (t >= off) ? sS[t - off] : 0;
        __syncthreads();
        if (t >= off) sS[t] += x;
        __syncthreads();
    }
    if (t < NCHUNK) partial[t] = (t == 0) ? 0 : sS[t - 1];
}

__global__ void scan3_k(int* __restrict__ rowptr, const int* __restrict__ partial) {
    int i = blockIdx.x * blockDim.x + threadIdx.x;
    if (i < NN) rowptr[i] += partial[i >> 10];
    if (i == 0) rowptr[NN] = NE;
}

// ---------------- CSR fill: entries[rowptr[d]+pos] = src ----------------
__global__ void fill_k(const int* __restrict__ src, const int* __restrict__ dst,
                       const int* __restrict__ rowptr,
                       int* __restrict__ cursor, int* __restrict__ entries) {
    int e = blockIdx.x * blockDim.x + threadIdx.x;
    if (e >= NE) return;
    int s = src[e], d = dst[e];
    int pos = atomicAdd(&cursor[d], 1);
    entries[rowptr[d] + pos] = s;
}

// ---------------- GEMM: out16[r] = (half)(dis[r] * (act(h)[r] @ W)) ----------------
template <bool RELU_IN>
__global__ void gemm64_k(const float* __restrict__ h, const float* __restrict__ W,
                         const float* __restrict__ dis, __half* __restrict__ out16) {
    __shared__ float wS[64 * 64];
    __shared__ float hS[32 * 64];
    int tid = threadIdx.x;
    int rbase = blockIdx.x * 32;

#pragma unroll
    for (int i = 0; i < 16; i++) wS[tid + i * 256] = W[tid + i * 256];
#pragma unroll
    for (int i = 0; i < 8; i++) {
        int idx = tid + i * 256;
        int r = rbase + (idx >> 6);
        float v = (r < NN) ? h[r * FD + (idx & 63)] : 0.0f;
        if (RELU_IN) v = fmaxf(v, 0.0f);
        hS[idx] = v;
    }
    __syncthreads();

    int col = tid & 63, rg = tid >> 6;
    float acc[8];
#pragma unroll
    for (int i = 0; i < 8; i++) acc[i] = 0.0f;

    for (int k = 0; k < 64; k++) {
        float w = wS[k * 64 + col];
#pragma unroll
        for (int i = 0; i < 8; i++)
            acc[i] = fmaf(hS[(rg * 8 + i) * 64 + k], w, acc[i]);
    }
#pragma unroll
    for (int i = 0; i < 8; i++) {
        int r = rbase + rg * 8 + i;
        if (r < NN) out16[r * FD + col] = __float2half(acc[i] * dis[r]);
    }
}

// ---------------- gather: agg[n] = b + dis[n]*(h2'[n] + sum_in h2'[src]) ----------------
__global__ void gather_k(const __half* __restrict__ h2p, const int* __restrict__ rowptr,
                         const int* __restrict__ entries, const float* __restrict__ dis,
                         const float* __restrict__ b, float* __restrict__ agg) {
    int n = (blockIdx.x * blockDim.x + threadIdx.x) >> 6;
    int lane = threadIdx.x & 63;
    if (n >= NN) return;
    int e0 = rowptr[n], e1 = rowptr[n + 1];

    float sum = __half2float(h2p[n * FD + lane]);  // self-loop term

    for (int base = e0; base < e1; base += 64) {
        int m = min(64, e1 - base);
        int ent = (base + lane < e1) ? entries[base + lane] : 0;
        int d = 0;
        for (; d + 3 < m; d += 4) {
            int s0 = __shfl(ent, d);
            int s1 = __shfl(ent, d + 1);
            int s2 = __shfl(ent, d + 2);
            int s3 = __shfl(ent, d + 3);
            float v0 = __half2float(h2p[s0 * FD + lane]);
            float v1 = __half2float(h2p[s1 * FD + lane]);
            float v2 = __half2float(h2p[s2 * FD + lane]);
            float v3 = __half2float(h2p[s3 * FD + lane]);
            sum += v0 + v1 + v2 + v3;
        }
        for (; d < m; d++) {
            int s0 = __shfl(ent, d);
            sum += __half2float(h2p[s0 * FD + lane]);
        }
    }
    agg[n * FD + lane] = b[lane] + dis[n] * sum;
}

// ---------------- pooling ----------------
__global__ void pool_acc_k(const float* __restrict__ h, const int* __restrict__ batch,
                           float* __restrict__ pool) {
    int wid = (blockIdx.x * blockDim.x + threadIdx.x) >> 6;
    int lane = threadIdx.x & 63;
    int n0 = wid * 32;
    if (n0 >= NN) return;
    int n1 = min(n0 + 32, NN);
    int g = batch[n0];
    float acc = 0.0f;
    for (int n = n0; n < n1; n++) {
        int gn = batch[n];
        if (gn != g) {
            atomicAdd(&pool[g * FD + lane], acc);
            acc = 0.0f;
            g = gn;
        }
        acc += h[n * FD + lane];
    }
    atomicAdd(&pool[g * FD + lane], acc);
}

__global__ void cnt_k(const int* __restrict__ batch, float* __restrict__ cnt) {
    int g = threadIdx.x;
    if (g >= NG) return;
    auto lb = [&](int key) {
        int lo = 0, hi = NN;
        while (lo < hi) {
            int mid = (lo + hi) >> 1;
            if (batch[mid] < key) lo = mid + 1; else hi = mid;
        }
        return lo;
    };
    cnt[g] = (float)(lb(g + 1) - lb(g));
}

__global__ void final_k(const float* __restrict__ pool, const float* __restrict__ cnt,
                        const float* __restrict__ lin_w, const float* __restrict__ lin_b,
                        float* __restrict__ out) {
    int g = blockIdx.x * blockDim.x + threadIdx.x;
    if (g >= NG) return;
    float c = fmaxf(cnt[g], 1.0f);
    float s = 0.0f;
    for (int f = 0; f < FD; f++) s += pool[g * FD + f] * lin_w[f];
    out[g] = s / c + lin_b[0];
}

extern "C" void kernel_launch(void* const* d_in, const int* in_sizes, int n_in,
                              void* d_out, int out_size, void* d_ws, size_t ws_size,
                              hipStream_t stream) {
    const float* x     = (const float*)d_in[0];
    const int*   src   = (const int*)d_in[1];
    const int*   dst   = ((const int*)d_in[1]) + NE;
    const int*   batch = (const int*)d_in[2];
    const float* W1 = (const float*)d_in[3];  const float* b1 = (const float*)d_in[4];
    const float* W2 = (const float*)d_in[5];  const float* b2 = (const float*)d_in[6];
    const float* W3 = (const float*)d_in[7];  const float* b3 = (const float*)d_in[8];
    const float* W4 = (const float*)d_in[9];  const float* b4 = (const float*)d_in[10];
    const float* lin_w = (const float*)d_in[11];
    const float* lin_b = (const float*)d_in[12];
    float* out = (float*)d_out;

    // workspace layout
    char* p = (char*)d_ws;
    float*  dis    = (float*)p;           p += (size_t)NN * 4;
    int*    degi   = (int*)p;             p += (size_t)NN * 4;
    int*    rowptr = (int*)p;             p += (size_t)(NN + 4) * 4;
    int*    cursor = (int*)p;             p += (size_t)NN * 4;
    int*    partial= (int*)p;             p += 256 * 4;
    int*    entries= (int*)p;             p += (size_t)NE * 4;
    __half* tmp16  = (__half*)p;          p += (size_t)NN * FD * 2;
    float*  bufA   = (float*)p;           p += (size_t)NN * FD * 4;
    float*  pool   = (float*)p;           p += (size_t)NG * FD * 4;
    float*  cnt    = (float*)p;           p += (size_t)NG * 4;

    const int NODE_GRID = (NN + 255) / 256;
    const int EDGE_GRID = (NE + 255) / 256;

    // ---- CSR build ----
    hipMemsetAsync(degi, 0, (size_t)NN * 4, stream);
    hipMemsetAsync(cursor, 0, (size_t)NN * 4, stream);
    deg_count_k<<<EDGE_GRID, 256, 0, stream>>>(dst, degi);
    dis_k<<<NODE_GRID, 256, 0, stream>>>(degi, dis);
    scan1_k<<<NCHUNK, 256, 0, stream>>>(degi, rowptr, partial);
    scan2_k<<<1, 256, 0, stream>>>(partial);
    scan3_k<<<NODE_GRID, 256, 0, stream>>>(rowptr, partial);
    fill_k<<<EDGE_GRID, 256, 0, stream>>>(src, dst, rowptr, cursor, entries);

    const int GEMM_GRID = (NN + 31) / 32;
    const int WAVE_GRID = ((size_t)NN * 64 + 255) / 256;

    // layer 1: x -> bufA
    gemm64_k<false><<<GEMM_GRID, 256, 0, stream>>>(x, W1, dis, tmp16);
    gather_k<<<WAVE_GRID, 256, 0, stream>>>(tmp16, rowptr, entries, dis, b1, bufA);
    // layer 2
    gemm64_k<true><<<GEMM_GRID, 256, 0, stream>>>(bufA, W2, dis, tmp16);
    gather_k<<<WAVE_GRID, 256, 0, stream>>>(tmp16, rowptr, entries, dis, b2, bufA);
    // layer 3
    gemm64_k<true><<<GEMM_GRID, 256, 0, stream>>>(bufA, W3, dis, tmp16);
    gather_k<<<WAVE_GRID, 256, 0, stream>>>(tmp16, rowptr, entries, dis, b3, bufA);
    // layer 4
    gemm64_k<true><<<GEMM_GRID, 256, 0, stream>>>(bufA, W4, dis, tmp16);
    gather_k<<<WAVE_GRID, 256, 0, stream>>>(tmp16, rowptr, entries, dis, b4, bufA);

    // pooling + final
    hipMemsetAsync(pool, 0, (size_t)NG * FD * 4, stream);
    pool_acc_k<<<((NN + 31) / 32 * 64 + 255) / 256, 256, 0, stream>>>(bufA, batch, pool);
    cnt_k<<<1, 128, 0, stream>>>(batch, cnt);
    final_k<<<1, 128, 0, stream>>>(pool, cnt, lin_w, lin_b, out);
}

// Round 5
// 408.396 us; speedup vs baseline: 3.9109x; 1.3336x over previous
//
#include <hip/hip_runtime.h>
#include <type_traits>

#define NN 100000
#define NE 1600000
#define FD 64
#define NG 128
#define NB ((NN + 255) >> 8)          // 391 buckets of 256 nodes
#define CAP 6144                      // per-bucket entry capacity in LDS
#define SCAN_CHUNK 1024
#define NCHUNK ((NN + SCAN_CHUNK - 1) / SCAN_CHUNK)   // 98

typedef _Float16 f16x8 __attribute__((ext_vector_type(8)));
typedef _Float16 f16x2 __attribute__((ext_vector_type(2)));
typedef float f32x4 __attribute__((ext_vector_type(4)));

// ---------------- degree count ----------------
__global__ void deg_count_k(const int* __restrict__ dst, int* __restrict__ degi) {
    int e = blockIdx.x * blockDim.x + threadIdx.x;
    if (e < NE) atomicAdd(&degi[dst[e]], 1);
}

__global__ void dis_k(const int* __restrict__ degi, float* __restrict__ dis) {
    int n = blockIdx.x * blockDim.x + threadIdx.x;
    if (n < NN) dis[n] = rsqrtf((float)degi[n] + 1.0f);
}

// ---------------- exclusive scan ----------------
__global__ void scan1_k(const int* __restrict__ cnt, int* __restrict__ rowptr,
                        int* __restrict__ partial) {
    __shared__ int sS[256];
    int t = threadIdx.x;
    int base = blockIdx.x * SCAN_CHUNK + t * 4;
    int v[4], s = 0;
#pragma unroll
    for (int i = 0; i < 4; i++) {
        int idx = base + i;
        v[i] = (idx < NN) ? cnt[idx] : 0;
        s += v[i];
    }
    sS[t] = s;
    __syncthreads();
    for (int off = 1; off < 256; off <<= 1) {
        int x = (t >= off) ? sS[t - off] : 0;
        __syncthreads();
        if (t >= off) sS[t] += x;
        __syncthreads();
    }
    int run = (t == 0) ? 0 : sS[t - 1];
    if (t == 255) partial[blockIdx.x] = sS[255];
#pragma unroll
    for (int i = 0; i < 4; i++) {
        int idx = base + i;
        if (idx < NN) rowptr[idx] = run;
        run += v[i];
    }
}

__global__ void scan2_k(int* __restrict__ partial) {
    __shared__ int sS[256];
    int t = threadIdx.x;
    sS[t] = (t < NCHUNK) ? partial[t] : 0;
    __syncthreads();
    for (int off = 1; off < 256; off <<= 1) {
        int x = (t >= off) ? sS[t - off] : 0;
        __syncthreads();
        if (t >= off) sS[t] += x;
        __syncthreads();
    }
    if (t < NCHUNK) partial[t] = (t == 0) ? 0 : sS[t - 1];
}

// also seeds per-bucket global cursors with the bucket's base offset
__global__ void scan3_k(int* __restrict__ rowptr, const int* __restrict__ partial,
                        int* __restrict__ gcursor) {
    int i = blockIdx.x * blockDim.x + threadIdx.x;
    if (i < NN) {
        int v = rowptr[i] + partial[i >> 10];
        rowptr[i] = v;
        if ((i & 255) == 0) gcursor[i >> 8] = v;
    }
    if (i == 0) rowptr[NN] = NE;
}

// ---------------- CSR pass 1: partition edges by dst>>8 ----------------
__global__ void part1_k(const int* __restrict__ src, const int* __restrict__ dst,
                        int* __restrict__ gcursor, int2* __restrict__ part) {
    __shared__ int hist[NB];
    __shared__ int resv[NB];
    __shared__ int lcur[NB];
    int t = threadIdx.x;
    for (int i = t; i < NB; i += 256) { hist[i] = 0; lcur[i] = 0; }
    __syncthreads();
    int base = blockIdx.x * 4096;
    int s[16], d[16];
#pragma unroll
    for (int i = 0; i < 16; i++) {
        int e = base + i * 256 + t;
        if (e < NE) {
            s[i] = src[e]; d[i] = dst[e];
            atomicAdd(&hist[d[i] >> 8], 1);
        } else d[i] = -1;
    }
    __syncthreads();
    for (int b = t; b < NB; b += 256)
        if (hist[b]) resv[b] = atomicAdd(&gcursor[b], hist[b]);
    __syncthreads();
#pragma unroll
    for (int i = 0; i < 16; i++) {
        if (d[i] >= 0) {
            int b = d[i] >> 8;
            int off = atomicAdd(&lcur[b], 1);
            part[resv[b] + off] = make_int2(s[i], d[i]);
        }
    }
}

// ---------------- CSR pass 2: per-bucket assembly in LDS, coalesced dump ----------------
__global__ void csr2_k(const int2* __restrict__ part, const int* __restrict__ rowptr,
                       int* __restrict__ entries) {
    __shared__ int rp[257];
    __shared__ int lcur[256];
    __shared__ int ebuf[CAP];
    int b = blockIdx.x;
    int n0 = b << 8;
    int nCnt = min(256, NN - n0);
    int t = threadIdx.x;
    if (t <= nCnt) rp[t] = rowptr[n0 + t];
    if (t == 0 && nCnt == 256) rp[256] = rowptr[n0 + 256];
    lcur[t] = 0;
    __syncthreads();
    int e0 = rp[0], e1 = rp[nCnt];
    int cnt = e1 - e0;
    for (int i = t; i < cnt; i += 256) {
        int2 e = part[e0 + i];
        int ln = e.y - n0;
        int pos = atomicAdd(&lcur[ln], 1);
        int idx = rp[ln] - e0 + pos;
        if (idx < CAP) ebuf[idx] = e.x;
        else entries[e0 + idx] = e.x;   // statistically never
    }
    __syncthreads();
    for (int i = t; i < cnt; i += 256)
        if (i < CAP) entries[e0 + i] = ebuf[i];
}

// ---------------- MFMA GEMM: out16[r] = fp16( dis[r] * (h[r] @ W) ) ----------------
template <typename TIN>
__global__ __launch_bounds__(256) void gemm_mfma_k(const TIN* __restrict__ h,
                                                   const float* __restrict__ W,
                                                   const float* __restrict__ dis,
                                                   _Float16* __restrict__ out16) {
    __shared__ _Float16 wT[64 * 76];   // W^T [c][k], padded stride 76
    __shared__ _Float16 oS[64 * 64];   // output staging
    int t = threadIdx.x;
    int wave = t >> 6, lane = t & 63;
    int m0 = blockIdx.x * 64 + wave * 16;
    int arow = min(m0 + (lane & 15), NN - 1);
    int kg = lane >> 4;

    // A fragments first (global, independent of LDS)
    f16x8 a0, a1;
    if constexpr (std::is_same<TIN, float>::value) {
        const float4* p0 = (const float4*)&h[(size_t)arow * 64 + kg * 8];
        const float4* p1 = (const float4*)&h[(size_t)arow * 64 + 32 + kg * 8];
        float4 x0 = p0[0], x1 = p0[1], y0 = p1[0], y1 = p1[1];
        a0[0] = (_Float16)x0.x; a0[1] = (_Float16)x0.y; a0[2] = (_Float16)x0.z; a0[3] = (_Float16)x0.w;
        a0[4] = (_Float16)x1.x; a0[5] = (_Float16)x1.y; a0[6] = (_Float16)x1.z; a0[7] = (_Float16)x1.w;
        a1[0] = (_Float16)y0.x; a1[1] = (_Float16)y0.y; a1[2] = (_Float16)y0.z; a1[3] = (_Float16)y0.w;
        a1[4] = (_Float16)y1.x; a1[5] = (_Float16)y1.y; a1[6] = (_Float16)y1.z; a1[7] = (_Float16)y1.w;
    } else {
        a0 = *(const f16x8*)&h[(size_t)arow * 64 + kg * 8];
        a1 = *(const f16x8*)&h[(size_t)arow * 64 + 32 + kg * 8];
    }

    for (int i = t; i < 4096; i += 256) {
        int k = i >> 6, c = i & 63;
        wT[c * 76 + k] = (_Float16)W[i];
    }
    __syncthreads();

    f32x4 acc[4];
#pragma unroll
    for (int i = 0; i < 4; i++) acc[i] = (f32x4){0.f, 0.f, 0.f, 0.f};

#pragma unroll
    for (int c0 = 0; c0 < 4; c0++) {
        const _Float16* wp = &wT[(c0 * 16 + (lane & 15)) * 76 + kg * 8];
        f16x8 b0 = *(const f16x8*)wp;
        f16x8 b1 = *(const f16x8*)(wp + 32);
        acc[c0] = __builtin_amdgcn_mfma_f32_16x16x32_f16(a0, b0, acc[c0], 0, 0, 0);
        acc[c0] = __builtin_amdgcn_mfma_f32_16x16x32_f16(a1, b1, acc[c0], 0, 0, 0);
    }

#pragma unroll
    for (int j = 0; j < 4; j++) {
        int row = (lane >> 4) * 4 + j;
        float dsc = dis[min(m0 + row, NN - 1)];
#pragma unroll
        for (int c0 = 0; c0 < 4; c0++)
            oS[(wave * 16 + row) * 64 + c0 * 16 + (lane & 15)] = (_Float16)(acc[c0][j] * dsc);
    }
    __syncthreads();

    int rbase = blockIdx.x * 64;
    for (int i = t; i < 512; i += 256) {      // 512 x 16B = 8KB
        int r = i >> 3;
        if (rbase + r < NN)
            ((int4*)&out16[(size_t)(rbase + r) * 64])[i & 7] = ((int4*)oS)[i];
    }
}

// ---------------- gather: half2 lanes, 2 edges per instruction ----------------
template <int LAST>
__global__ void gather_k(const _Float16* __restrict__ h2p, const int* __restrict__ rowptr,
                         const int* __restrict__ entries, const float* __restrict__ dis,
                         const float* __restrict__ bias, _Float16* __restrict__ out16,
                         float* __restrict__ outf) {
    int n = (blockIdx.x * blockDim.x + threadIdx.x) >> 6;
    if (n >= NN) return;
    int lane = threadIdx.x & 63;
    int hf = lane >> 5;            // which edge of the pair
    int fl = (lane & 31) * 2;      // feature pair

    int e0 = rowptr[n], e1 = rowptr[n + 1];
    // self term ONCE (hf==0 half only; hf==1 half starts at zero)
    float sx = 0.f, sy = 0.f;
    if (hf == 0) {
        f16x2 sv = *(const f16x2*)&h2p[(size_t)n * 64 + fl];
        sx = (float)sv[0]; sy = (float)sv[1];
    }

    for (int base = e0; base < e1; base += 64) {
        int m = min(64, e1 - base);
        int ent = (base + lane < e1) ? entries[base + lane] : 0;
        int d = 0;
        for (; d + 15 < m; d += 16) {
            int s0 = __shfl(ent, d + 0 + hf);
            int s1 = __shfl(ent, d + 2 + hf);
            int s2 = __shfl(ent, d + 4 + hf);
            int s3 = __shfl(ent, d + 6 + hf);
            int s4 = __shfl(ent, d + 8 + hf);
            int s5 = __shfl(ent, d + 10 + hf);
            int s6 = __shfl(ent, d + 12 + hf);
            int s7 = __shfl(ent, d + 14 + hf);
            f16x2 v0 = *(const f16x2*)&h2p[(size_t)s0 * 64 + fl];
            f16x2 v1 = *(const f16x2*)&h2p[(size_t)s1 * 64 + fl];
            f16x2 v2 = *(const f16x2*)&h2p[(size_t)s2 * 64 + fl];
            f16x2 v3 = *(const f16x2*)&h2p[(size_t)s3 * 64 + fl];
            f16x2 v4 = *(const f16x2*)&h2p[(size_t)s4 * 64 + fl];
            f16x2 v5 = *(const f16x2*)&h2p[(size_t)s5 * 64 + fl];
            f16x2 v6 = *(const f16x2*)&h2p[(size_t)s6 * 64 + fl];
            f16x2 v7 = *(const f16x2*)&h2p[(size_t)s7 * 64 + fl];
            sx += (((float)v0[0] + (float)v1[0]) + ((float)v2[0] + (float)v3[0])) +
                  (((float)v4[0] + (float)v5[0]) + ((float)v6[0] + (float)v7[0]));
            sy += (((float)v0[1] + (float)v1[1]) + ((float)v2[1] + (float)v3[1])) +
                  (((float)v4[1] + (float)v5[1]) + ((float)v6[1] + (float)v7[1]));
        }
        for (; d + 1 < m; d += 2) {
            int s = __shfl(ent, d + hf);
            f16x2 v = *(const f16x2*)&h2p[(size_t)s * 64 + fl];
            sx += (float)v[0]; sy += (float)v[1];
        }
        if (d < m) {
            int s = __shfl(ent, d);
            if (hf == 0) {
                f16x2 v = *(const f16x2*)&h2p[(size_t)s * 64 + fl];
                sx += (float)v[0]; sy += (float)v[1];
            }
        }
    }
    sx += __shfl_xor(sx, 32);
    sy += __shfl_xor(sy, 32);
    if (hf == 0) {
        float dn = dis[n];
        float ax = bias[fl] + dn * sx;
        float ay = bias[fl + 1] + dn * sy;
        if (LAST) {
            float2 o = make_float2(ax, ay);
            *(float2*)&outf[(size_t)n * 64 + fl] = o;
        } else {
            f16x2 o;
            o[0] = (_Float16)fmaxf(ax, 0.f);
            o[1] = (_Float16)fmaxf(ay, 0.f);
            *(f16x2*)&out16[(size_t)n * 64 + fl] = o;
        }
    }
}

// ---------------- pooling ----------------
__global__ void pool_acc_k(const float* __restrict__ h, const int* __restrict__ batch,
                           float* __restrict__ pool) {
    int wid = (blockIdx.x * blockDim.x + threadIdx.x) >> 6;
    int lane = threadIdx.x & 63;
    int n0 = wid * 32;
    if (n0 >= NN) return;
    int n1 = min(n0 + 32, NN);
    int g = batch[n0];
    float acc = 0.0f;
    for (int n = n0; n < n1; n++) {
        int gn = batch[n];
        if (gn != g) {
            atomicAdd(&pool[g * FD + lane], acc);
            acc = 0.0f;
            g = gn;
        }
        acc += h[(size_t)n * FD + lane];
    }
    atomicAdd(&pool[g * FD + lane], acc);
}

__global__ void cnt_k(const int* __restrict__ batch, float* __restrict__ cnt) {
    int g = threadIdx.x;
    if (g >= NG) return;
    auto lb = [&](int key) {
        int lo = 0, hi = NN;
        while (lo < hi) {
            int mid = (lo + hi) >> 1;
            if (batch[mid] < key) lo = mid + 1; else hi = mid;
        }
        return lo;
    };
    cnt[g] = (float)(lb(g + 1) - lb(g));
}

__global__ void final_k(const float* __restrict__ pool, const float* __restrict__ cnt,
                        const float* __restrict__ lin_w, const float* __restrict__ lin_b,
                        float* __restrict__ out) {
    int g = blockIdx.x * blockDim.x + threadIdx.x;
    if (g >= NG) return;
    float c = fmaxf(cnt[g], 1.0f);
    float s = 0.0f;
    for (int f = 0; f < FD; f++) s += pool[g * FD + f] * lin_w[f];
    out[g] = s / c + lin_b[0];
}

extern "C" void kernel_launch(void* const* d_in, const int* in_sizes, int n_in,
                              void* d_out, int out_size, void* d_ws, size_t ws_size,
                              hipStream_t stream) {
    const float* x     = (const float*)d_in[0];
    const int*   src   = (const int*)d_in[1];
    const int*   dst   = ((const int*)d_in[1]) + NE;
    const int*   batch = (const int*)d_in[2];
    const float* W1 = (const float*)d_in[3];  const float* b1 = (const float*)d_in[4];
    const float* W2 = (const float*)d_in[5];  const float* b2 = (const float*)d_in[6];
    const float* W3 = (const float*)d_in[7];  const float* b3 = (const float*)d_in[8];
    const float* W4 = (const float*)d_in[9];  const float* b4 = (const float*)d_in[10];
    const float* lin_w = (const float*)d_in[11];
    const float* lin_b = (const float*)d_in[12];
    float* out = (float*)d_out;

    // workspace layout (part overlays aggf: part dead before gather4 writes aggf)
    char* p = (char*)d_ws;
    float*    aggf    = (float*)p;                 // NN*FD fp32 (25.6MB)
    int2*     part    = (int2*)p;     p += (size_t)NN * FD * 4;
    _Float16* h16a    = (_Float16*)p; p += (size_t)NN * FD * 2;   // gather out / gemm in
    _Float16* h16b    = (_Float16*)p; p += (size_t)NN * FD * 2;   // gemm out
    int*      entries = (int*)p;      p += (size_t)NE * 4;
    float*    dis     = (float*)p;    p += (size_t)NN * 4;
    int*      degi    = (int*)p;      p += (size_t)NN * 4;
    int*      rowptr  = (int*)p;      p += (size_t)(NN + 4) * 4;
    int*      partial = (int*)p;      p += 256 * 4;
    int*      gcursor = (int*)p;      p += ((NB + 3) & ~3) * 4;
    float*    pool    = (float*)p;    p += (size_t)NG * FD * 4;
    float*    cnt     = (float*)p;    p += (size_t)NG * 4;

    const int NODE_GRID = (NN + 255) / 256;
    const int EDGE_GRID = (NE + 255) / 256;

    // ---- CSR build ----
    hipMemsetAsync(degi, 0, (size_t)NN * 4, stream);
    deg_count_k<<<EDGE_GRID, 256, 0, stream>>>(dst, degi);
    dis_k<<<NODE_GRID, 256, 0, stream>>>(degi, dis);
    scan1_k<<<NCHUNK, 256, 0, stream>>>(degi, rowptr, partial);
    scan2_k<<<1, 256, 0, stream>>>(partial);
    scan3_k<<<NODE_GRID, 256, 0, stream>>>(rowptr, partial, gcursor);
    part1_k<<<(NE + 4095) / 4096, 256, 0, stream>>>(src, dst, gcursor, part);
    csr2_k<<<NB, 256, 0, stream>>>(part, rowptr, entries);

    const int GEMM_GRID = (NN + 63) / 64;
    const int WAVE_GRID = ((size_t)NN * 64 + 255) / 256;

    gemm_mfma_k<float><<<GEMM_GRID, 256, 0, stream>>>(x, W1, dis, h16b);
    gather_k<0><<<WAVE_GRID, 256, 0, stream>>>(h16b, rowptr, entries, dis, b1, h16a, nullptr);
    gemm_mfma_k<_Float16><<<GEMM_GRID, 256, 0, stream>>>(h16a, W2, dis, h16b);
    gather_k<0><<<WAVE_GRID, 256, 0, stream>>>(h16b, rowptr, entries, dis, b2, h16a, nullptr);
    gemm_mfma_k<_Float16><<<GEMM_GRID, 256, 0, stream>>>(h16a, W3, dis, h16b);
    gather_k<0><<<WAVE_GRID, 256, 0, stream>>>(h16b, rowptr, entries, dis, b3, h16a, nullptr);
    gemm_mfma_k<_Float16><<<GEMM_GRID, 256, 0, stream>>>(h16a, W4, dis, h16b);
    gather_k<1><<<WAVE_GRID, 256, 0, stream>>>(h16b, rowptr, entries, dis, b4, nullptr, aggf);

    // ---- pooling + final ----
    hipMemsetAsync(pool, 0, (size_t)NG * FD * 4, stream);
    pool_acc_k<<<((NN + 31) / 32 * 64 + 255) / 256, 256, 0, stream>>>(aggf, batch, pool);
    cnt_k<<<1, 128, 0, stream>>>(batch, cnt);
    final_k<<<1, 128, 0, stream>>>(pool, cnt, lin_w, lin_b, out);
}

// Round 6
// 355.617 us; speedup vs baseline: 4.4914x; 1.1484x over previous
//
#include <hip/hip_runtime.h>
#include <type_traits>

#define NN 100000
#define NE 1600000
#define FD 64
#define NG 128
#define NB ((NN + 255) >> 8)          // 391 buckets of 256 nodes
#define CAP 6144                      // per-bucket entry capacity in LDS
#define SRCMASK 0x1FFFF               // src < 100000 < 2^17

typedef _Float16 f16x8 __attribute__((ext_vector_type(8)));
typedef _Float16 f16x2 __attribute__((ext_vector_type(2)));
typedef float f32x4 __attribute__((ext_vector_type(4)));

// ---------------- bucket histogram (LDS-aggregated) ----------------
__global__ void bhist_k(const int* __restrict__ dst, int* __restrict__ bhist) {
    __shared__ int h[NB];
    int t = threadIdx.x;
    for (int i = t; i < NB; i += 256) h[i] = 0;
    __syncthreads();
    int base = blockIdx.x * 4096;
#pragma unroll
    for (int i = 0; i < 16; i++) {
        int e = base + i * 256 + t;
        if (e < NE) atomicAdd(&h[dst[e] >> 8], 1);
    }
    __syncthreads();
    for (int i = t; i < NB; i += 256)
        if (h[i]) atomicAdd(&bhist[i], h[i]);
}

// ---------------- bucket scan -> bucket bases + partition cursors ----------------
__global__ void bscan_k(const int* __restrict__ bhist, int* __restrict__ bbase,
                        int* __restrict__ gcursor) {
    __shared__ int sS[512];
    int t = threadIdx.x;
    sS[t] = (t < NB) ? bhist[t] : 0;
    __syncthreads();
    for (int off = 1; off < 512; off <<= 1) {
        int x = (t >= off) ? sS[t - off] : 0;
        __syncthreads();
        if (t >= off) sS[t] += x;
        __syncthreads();
    }
    int excl = (t == 0) ? 0 : sS[t - 1];
    if (t < NB) { bbase[t] = excl; gcursor[t] = excl; }
    if (t == NB) bbase[NB] = NE;
}

// ---------------- partition edges by dst>>8, packed 4B entries ----------------
__global__ void part1_k(const int* __restrict__ src, const int* __restrict__ dst,
                        int* __restrict__ gcursor, int* __restrict__ part) {
    __shared__ int hist[NB];
    __shared__ int resv[NB];
    __shared__ int lcur[NB];
    int t = threadIdx.x;
    for (int i = t; i < NB; i += 256) { hist[i] = 0; lcur[i] = 0; }
    __syncthreads();
    int base = blockIdx.x * 4096;
    int s[16], d[16];
#pragma unroll
    for (int i = 0; i < 16; i++) {
        int e = base + i * 256 + t;
        if (e < NE) {
            s[i] = src[e]; d[i] = dst[e];
            atomicAdd(&hist[d[i] >> 8], 1);
        } else d[i] = -1;
    }
    __syncthreads();
    for (int b = t; b < NB; b += 256)
        if (hist[b]) resv[b] = atomicAdd(&gcursor[b], hist[b]);
    __syncthreads();
#pragma unroll
    for (int i = 0; i < 16; i++) {
        if (d[i] >= 0) {
            int b = d[i] >> 8;
            int off = atomicAdd(&lcur[b], 1);
            part[resv[b] + off] = s[i] | ((d[i] & 255) << 17);
        }
    }
}

// ---------------- per-bucket: LDS degree count + scan -> rowptr, dis, entries ----------------
__global__ void csr2_k(const int* __restrict__ part, const int* __restrict__ bbase,
                       int* __restrict__ rowptr, float* __restrict__ dis,
                       int* __restrict__ entries) {
    __shared__ int sA[CAP];
    __shared__ int sB[CAP];
    __shared__ int cntL[256];
    __shared__ int posL[256];
    __shared__ int locL[256];
    int b = blockIdx.x, t = threadIdx.x;
    int n0 = b << 8;
    int nCnt = min(256, NN - n0);
    cntL[t] = 0; posL[t] = 0;
    __syncthreads();
    int e0 = bbase[b], e1 = bbase[b + 1];
    int cnt = e1 - e0;

    // pass A: stage raw packed edges in LDS, count per-node degree
    for (int i = t; i < cnt; i += 256) {
        int pk = part[e0 + i];
        if (i < CAP) sA[i] = pk;
        atomicAdd(&cntL[(pk >> 17) & 255], 1);
    }
    __syncthreads();

    // inclusive scan of counts -> locL, then exclusive
    locL[t] = cntL[t];
    __syncthreads();
    for (int off = 1; off < 256; off <<= 1) {
        int x = (t >= off) ? locL[t - off] : 0;
        __syncthreads();
        if (t >= off) locL[t] += x;
        __syncthreads();
    }
    int excl = (t == 0) ? 0 : locL[t - 1];
    __syncthreads();
    locL[t] = excl;
    __syncthreads();

    if (t < nCnt) {
        rowptr[n0 + t] = e0 + locL[t];
        dis[n0 + t] = rsqrtf((float)cntL[t] + 1.0f);
    }
    if (b == NB - 1 && t == 0) rowptr[NN] = NE;

    // pass B: place src into per-node slots
    for (int i = t; i < cnt; i += 256) {
        int pk = (i < CAP) ? sA[i] : part[e0 + i];
        int ln = (pk >> 17) & 255;
        int sv = pk & SRCMASK;
        int pos = atomicAdd(&posL[ln], 1);
        int idx = locL[ln] + pos;
        if (idx < CAP) sB[idx] = sv;
        else entries[e0 + idx] = sv;   // statistically never
    }
    __syncthreads();
    int lim = min(cnt, CAP);
    for (int i = t; i < lim; i += 256)
        entries[e0 + i] = sB[i];
}

// ---------------- MFMA GEMM: out16[r] = fp16( dis[r] * (h[r] @ W) ) ----------------
template <typename TIN>
__global__ __launch_bounds__(256) void gemm_mfma_k(const TIN* __restrict__ h,
                                                   const float* __restrict__ W,
                                                   const float* __restrict__ dis,
                                                   _Float16* __restrict__ out16) {
    __shared__ _Float16 wT[64 * 76];   // W^T [c][k], padded stride 76
    __shared__ _Float16 oS[64 * 64];   // output staging
    int t = threadIdx.x;
    int wave = t >> 6, lane = t & 63;
    int m0 = blockIdx.x * 64 + wave * 16;
    int arow = min(m0 + (lane & 15), NN - 1);
    int kg = lane >> 4;

    f16x8 a0, a1;
    if constexpr (std::is_same<TIN, float>::value) {
        const float4* p0 = (const float4*)&h[(size_t)arow * 64 + kg * 8];
        const float4* p1 = (const float4*)&h[(size_t)arow * 64 + 32 + kg * 8];
        float4 x0 = p0[0], x1 = p0[1], y0 = p1[0], y1 = p1[1];
        a0[0] = (_Float16)x0.x; a0[1] = (_Float16)x0.y; a0[2] = (_Float16)x0.z; a0[3] = (_Float16)x0.w;
        a0[4] = (_Float16)x1.x; a0[5] = (_Float16)x1.y; a0[6] = (_Float16)x1.z; a0[7] = (_Float16)x1.w;
        a1[0] = (_Float16)y0.x; a1[1] = (_Float16)y0.y; a1[2] = (_Float16)y0.z; a1[3] = (_Float16)y0.w;
        a1[4] = (_Float16)y1.x; a1[5] = (_Float16)y1.y; a1[6] = (_Float16)y1.z; a1[7] = (_Float16)y1.w;
    } else {
        a0 = *(const f16x8*)&h[(size_t)arow * 64 + kg * 8];
        a1 = *(const f16x8*)&h[(size_t)arow * 64 + 32 + kg * 8];
    }

    for (int i = t; i < 4096; i += 256) {
        int k = i >> 6, c = i & 63;
        wT[c * 76 + k] = (_Float16)W[i];
    }
    __syncthreads();

    f32x4 acc[4];
#pragma unroll
    for (int i = 0; i < 4; i++) acc[i] = (f32x4){0.f, 0.f, 0.f, 0.f};

#pragma unroll
    for (int c0 = 0; c0 < 4; c0++) {
        const _Float16* wp = &wT[(c0 * 16 + (lane & 15)) * 76 + kg * 8];
        f16x8 b0 = *(const f16x8*)wp;
        f16x8 b1 = *(const f16x8*)(wp + 32);
        acc[c0] = __builtin_amdgcn_mfma_f32_16x16x32_f16(a0, b0, acc[c0], 0, 0, 0);
        acc[c0] = __builtin_amdgcn_mfma_f32_16x16x32_f16(a1, b1, acc[c0], 0, 0, 0);
    }

#pragma unroll
    for (int j = 0; j < 4; j++) {
        int row = (lane >> 4) * 4 + j;
        float dsc = dis[min(m0 + row, NN - 1)];
#pragma unroll
        for (int c0 = 0; c0 < 4; c0++)
            oS[(wave * 16 + row) * 64 + c0 * 16 + (lane & 15)] = (_Float16)(acc[c0][j] * dsc);
    }
    __syncthreads();

    int rbase = blockIdx.x * 64;
    for (int i = t; i < 512; i += 256) {
        int r = i >> 3;
        if (rbase + r < NN)
            ((int4*)&out16[(size_t)(rbase + r) * 64])[i & 7] = ((int4*)oS)[i];
    }
}

// ---------------- gather: half2 lanes, 2 edges per instruction ----------------
template <int LAST>
__global__ void gather_k(const _Float16* __restrict__ h2p, const int* __restrict__ rowptr,
                         const int* __restrict__ entries, const float* __restrict__ dis,
                         const float* __restrict__ bias, _Float16* __restrict__ out16,
                         float* __restrict__ outf) {
    int n = (blockIdx.x * blockDim.x + threadIdx.x) >> 6;
    if (n >= NN) return;
    int lane = threadIdx.x & 63;
    int hf = lane >> 5;            // which edge of the pair
    int fl = (lane & 31) * 2;      // feature pair

    int e0 = rowptr[n], e1 = rowptr[n + 1];
    float sx = 0.f, sy = 0.f;
    if (hf == 0) {                  // self term counted once
        f16x2 sv = *(const f16x2*)&h2p[(size_t)n * 64 + fl];
        sx = (float)sv[0]; sy = (float)sv[1];
    }

    for (int base = e0; base < e1; base += 64) {
        int m = min(64, e1 - base);
        int ent = (base + lane < e1) ? entries[base + lane] : 0;
        int d = 0;
        for (; d + 15 < m; d += 16) {
            int s0 = __shfl(ent, d + 0 + hf);
            int s1 = __shfl(ent, d + 2 + hf);
            int s2 = __shfl(ent, d + 4 + hf);
            int s3 = __shfl(ent, d + 6 + hf);
            int s4 = __shfl(ent, d + 8 + hf);
            int s5 = __shfl(ent, d + 10 + hf);
            int s6 = __shfl(ent, d + 12 + hf);
            int s7 = __shfl(ent, d + 14 + hf);
            f16x2 v0 = *(const f16x2*)&h2p[(size_t)s0 * 64 + fl];
            f16x2 v1 = *(const f16x2*)&h2p[(size_t)s1 * 64 + fl];
            f16x2 v2 = *(const f16x2*)&h2p[(size_t)s2 * 64 + fl];
            f16x2 v3 = *(const f16x2*)&h2p[(size_t)s3 * 64 + fl];
            f16x2 v4 = *(const f16x2*)&h2p[(size_t)s4 * 64 + fl];
            f16x2 v5 = *(const f16x2*)&h2p[(size_t)s5 * 64 + fl];
            f16x2 v6 = *(const f16x2*)&h2p[(size_t)s6 * 64 + fl];
            f16x2 v7 = *(const f16x2*)&h2p[(size_t)s7 * 64 + fl];
            sx += (((float)v0[0] + (float)v1[0]) + ((float)v2[0] + (float)v3[0])) +
                  (((float)v4[0] + (float)v5[0]) + ((float)v6[0] + (float)v7[0]));
            sy += (((float)v0[1] + (float)v1[1]) + ((float)v2[1] + (float)v3[1])) +
                  (((float)v4[1] + (float)v5[1]) + ((float)v6[1] + (float)v7[1]));
        }
        for (; d + 1 < m; d += 2) {
            int s = __shfl(ent, d + hf);
            f16x2 v = *(const f16x2*)&h2p[(size_t)s * 64 + fl];
            sx += (float)v[0]; sy += (float)v[1];
        }
        if (d < m) {
            int s = __shfl(ent, d);
            if (hf == 0) {
                f16x2 v = *(const f16x2*)&h2p[(size_t)s * 64 + fl];
                sx += (float)v[0]; sy += (float)v[1];
            }
        }
    }
    sx += __shfl_xor(sx, 32);
    sy += __shfl_xor(sy, 32);
    if (hf == 0) {
        float dn = dis[n];
        float ax = bias[fl] + dn * sx;
        float ay = bias[fl + 1] + dn * sy;
        if (LAST) {
            float2 o = make_float2(ax, ay);
            *(float2*)&outf[(size_t)n * 64 + fl] = o;
        } else {
            f16x2 o;
            o[0] = (_Float16)fmaxf(ax, 0.f);
            o[1] = (_Float16)fmaxf(ay, 0.f);
            *(f16x2*)&out16[(size_t)n * 64 + fl] = o;
        }
    }
}

// ---------------- pooling ----------------
__global__ void pool_acc_k(const float* __restrict__ h, const int* __restrict__ batch,
                           float* __restrict__ pool) {
    int wid = (blockIdx.x * blockDim.x + threadIdx.x) >> 6;
    int lane = threadIdx.x & 63;
    int n0 = wid * 32;
    if (n0 >= NN) return;
    int n1 = min(n0 + 32, NN);
    int g = batch[n0];
    float acc = 0.0f;
    for (int n = n0; n < n1; n++) {
        int gn = batch[n];
        if (gn != g) {
            atomicAdd(&pool[g * FD + lane], acc);
            acc = 0.0f;
            g = gn;
        }
        acc += h[(size_t)n * FD + lane];
    }
    atomicAdd(&pool[g * FD + lane], acc);
}

__global__ void cnt_k(const int* __restrict__ batch, float* __restrict__ cnt) {
    int g = threadIdx.x;
    if (g >= NG) return;
    auto lb = [&](int key) {
        int lo = 0, hi = NN;
        while (lo < hi) {
            int mid = (lo + hi) >> 1;
            if (batch[mid] < key) lo = mid + 1; else hi = mid;
        }
        return lo;
    };
    cnt[g] = (float)(lb(g + 1) - lb(g));
}

__global__ void final_k(const float* __restrict__ pool, const float* __restrict__ cnt,
                        const float* __restrict__ lin_w, const float* __restrict__ lin_b,
                        float* __restrict__ out) {
    int g = blockIdx.x * blockDim.x + threadIdx.x;
    if (g >= NG) return;
    float c = fmaxf(cnt[g], 1.0f);
    float s = 0.0f;
    for (int f = 0; f < FD; f++) s += pool[g * FD + f] * lin_w[f];
    out[g] = s / c + lin_b[0];
}

extern "C" void kernel_launch(void* const* d_in, const int* in_sizes, int n_in,
                              void* d_out, int out_size, void* d_ws, size_t ws_size,
                              hipStream_t stream) {
    const float* x     = (const float*)d_in[0];
    const int*   src   = (const int*)d_in[1];
    const int*   dst   = ((const int*)d_in[1]) + NE;
    const int*   batch = (const int*)d_in[2];
    const float* W1 = (const float*)d_in[3];  const float* b1 = (const float*)d_in[4];
    const float* W2 = (const float*)d_in[5];  const float* b2 = (const float*)d_in[6];
    const float* W3 = (const float*)d_in[7];  const float* b3 = (const float*)d_in[8];
    const float* W4 = (const float*)d_in[9];  const float* b4 = (const float*)d_in[10];
    const float* lin_w = (const float*)d_in[11];
    const float* lin_b = (const float*)d_in[12];
    float* out = (float*)d_out;

    // workspace layout (part overlays aggf: part dead before gather4 writes aggf)
    char* p = (char*)d_ws;
    float*    aggf    = (float*)p;                 // NN*FD fp32 (25.6MB)
    int*      part    = (int*)p;      p += (size_t)NN * FD * 4;   // packed edges (6.4MB, overlaid)
    _Float16* h16a    = (_Float16*)p; p += (size_t)NN * FD * 2;   // gather out / gemm in
    _Float16* h16b    = (_Float16*)p; p += (size_t)NN * FD * 2;   // gemm out
    int*      entries = (int*)p;      p += (size_t)NE * 4;
    float*    dis     = (float*)p;    p += (size_t)NN * 4;
    int*      rowptr  = (int*)p;      p += (size_t)(NN + 4) * 4;
    int*      bhist   = (int*)p;      p += ((NB + 3) & ~3) * 4;
    int*      bbase   = (int*)p;      p += ((NB + 4) & ~3) * 4;
    int*      gcursor = (int*)p;      p += ((NB + 3) & ~3) * 4;
    float*    pool    = (float*)p;    p += (size_t)NG * FD * 4;
    float*    cnt     = (float*)p;    p += (size_t)NG * 4;

    const int EGRID = (NE + 4095) / 4096;   // 391

    // ---- CSR build (no per-node global atomics anywhere) ----
    hipMemsetAsync(bhist, 0, NB * 4, stream);
    bhist_k<<<EGRID, 256, 0, stream>>>(dst, bhist);
    bscan_k<<<1, 512, 0, stream>>>(bhist, bbase, gcursor);
    part1_k<<<EGRID, 256, 0, stream>>>(src, dst, gcursor, part);
    csr2_k<<<NB, 256, 0, stream>>>(part, bbase, rowptr, dis, entries);

    const int GEMM_GRID = (NN + 63) / 64;
    const int WAVE_GRID = ((size_t)NN * 64 + 255) / 256;

    gemm_mfma_k<float><<<GEMM_GRID, 256, 0, stream>>>(x, W1, dis, h16b);
    gather_k<0><<<WAVE_GRID, 256, 0, stream>>>(h16b, rowptr, entries, dis, b1, h16a, nullptr);
    gemm_mfma_k<_Float16><<<GEMM_GRID, 256, 0, stream>>>(h16a, W2, dis, h16b);
    gather_k<0><<<WAVE_GRID, 256, 0, stream>>>(h16b, rowptr, entries, dis, b2, h16a, nullptr);
    gemm_mfma_k<_Float16><<<GEMM_GRID, 256, 0, stream>>>(h16a, W3, dis, h16b);
    gather_k<0><<<WAVE_GRID, 256, 0, stream>>>(h16b, rowptr, entries, dis, b3, h16a, nullptr);
    gemm_mfma_k<_Float16><<<GEMM_GRID, 256, 0, stream>>>(h16a, W4, dis, h16b);
    gather_k<1><<<WAVE_GRID, 256, 0, stream>>>(h16b, rowptr, entries, dis, b4, nullptr, aggf);

    // ---- pooling + final ----
    hipMemsetAsync(pool, 0, (size_t)NG * FD * 4, stream);
    pool_acc_k<<<((NN + 31) / 32 * 64 + 255) / 256, 256, 0, stream>>>(aggf, batch, pool);
    cnt_k<<<1, 128, 0, stream>>>(batch, cnt);
    final_k<<<1, 128, 0, stream>>>(pool, cnt, lin_w, lin_b, out);
}

// Round 7
// 313.176 us; speedup vs baseline: 5.1000x; 1.1355x over previous
//
#include <hip/hip_runtime.h>
#include <type_traits>

#define NN 100000
#define NE 1600000
#define FD 64
#define NG 128
#define NB ((NN + 255) >> 8)          // 391 buckets of 256 nodes
#define CAP 6144                      // per-bucket entry capacity in LDS
#define SRCMASK 0x1FFFF               // src < 100000 < 2^17
#define ZR NN                         // zero-row index in h16b

typedef _Float16 f16x8 __attribute__((ext_vector_type(8)));
typedef _Float16 f16x4 __attribute__((ext_vector_type(4)));
typedef _Float16 f16x2 __attribute__((ext_vector_type(2)));
typedef float f32x4 __attribute__((ext_vector_type(4)));

// ---------------- bucket histogram (LDS-aggregated) ----------------
__global__ void bhist_k(const int* __restrict__ dst, int* __restrict__ bhist) {
    __shared__ int h[NB];
    int t = threadIdx.x;
    for (int i = t; i < NB; i += 256) h[i] = 0;
    __syncthreads();
    int base = blockIdx.x * 4096;
#pragma unroll
    for (int i = 0; i < 16; i++) {
        int e = base + i * 256 + t;
        if (e < NE) atomicAdd(&h[dst[e] >> 8], 1);
    }
    __syncthreads();
    for (int i = t; i < NB; i += 256)
        if (h[i]) atomicAdd(&bhist[i], h[i]);
}

// ---------------- bucket scan -> bucket bases + partition cursors ----------------
__global__ void bscan_k(const int* __restrict__ bhist, int* __restrict__ bbase,
                        int* __restrict__ gcursor) {
    __shared__ int sS[512];
    int t = threadIdx.x;
    sS[t] = (t < NB) ? bhist[t] : 0;
    __syncthreads();
    for (int off = 1; off < 512; off <<= 1) {
        int x = (t >= off) ? sS[t - off] : 0;
        __syncthreads();
        if (t >= off) sS[t] += x;
        __syncthreads();
    }
    int excl = (t == 0) ? 0 : sS[t - 1];
    if (t < NB) { bbase[t] = excl; gcursor[t] = excl; }
    if (t == NB) bbase[NB] = NE;
}

// ---------------- partition edges by dst>>8, packed 4B entries ----------------
__global__ void part1_k(const int* __restrict__ src, const int* __restrict__ dst,
                        int* __restrict__ gcursor, int* __restrict__ part) {
    __shared__ int hist[NB];
    __shared__ int resv[NB];
    __shared__ int lcur[NB];
    int t = threadIdx.x;
    for (int i = t; i < NB; i += 256) { hist[i] = 0; lcur[i] = 0; }
    __syncthreads();
    int base = blockIdx.x * 4096;
    int s[16], d[16];
#pragma unroll
    for (int i = 0; i < 16; i++) {
        int e = base + i * 256 + t;
        if (e < NE) {
            s[i] = src[e]; d[i] = dst[e];
            atomicAdd(&hist[d[i] >> 8], 1);
        } else d[i] = -1;
    }
    __syncthreads();
    for (int b = t; b < NB; b += 256)
        if (hist[b]) resv[b] = atomicAdd(&gcursor[b], hist[b]);
    __syncthreads();
#pragma unroll
    for (int i = 0; i < 16; i++) {
        if (d[i] >= 0) {
            int b = d[i] >> 8;
            int off = atomicAdd(&lcur[b], 1);
            part[resv[b] + off] = s[i] | ((d[i] & 255) << 17);
        }
    }
}

// ---------------- per-bucket: LDS degree count + scan -> rowptr, dis, entries ----------------
__global__ void csr2_k(const int* __restrict__ part, const int* __restrict__ bbase,
                       int* __restrict__ rowptr, float* __restrict__ dis,
                       int* __restrict__ entries) {
    __shared__ int sA[CAP];
    __shared__ int sB[CAP];
    __shared__ int cntL[256];
    __shared__ int posL[256];
    __shared__ int locL[256];
    int b = blockIdx.x, t = threadIdx.x;
    int n0 = b << 8;
    int nCnt = min(256, NN - n0);
    cntL[t] = 0; posL[t] = 0;
    __syncthreads();
    int e0 = bbase[b], e1 = bbase[b + 1];
    int cnt = e1 - e0;

    for (int i = t; i < cnt; i += 256) {
        int pk = part[e0 + i];
        if (i < CAP) sA[i] = pk;
        atomicAdd(&cntL[(pk >> 17) & 255], 1);
    }
    __syncthreads();

    locL[t] = cntL[t];
    __syncthreads();
    for (int off = 1; off < 256; off <<= 1) {
        int x = (t >= off) ? locL[t - off] : 0;
        __syncthreads();
        if (t >= off) locL[t] += x;
        __syncthreads();
    }
    int excl = (t == 0) ? 0 : locL[t - 1];
    __syncthreads();
    locL[t] = excl;
    __syncthreads();

    if (t < nCnt) {
        rowptr[n0 + t] = e0 + locL[t];
        dis[n0 + t] = rsqrtf((float)cntL[t] + 1.0f);
    }
    if (b == NB - 1 && t == 0) rowptr[NN] = NE;

    for (int i = t; i < cnt; i += 256) {
        int pk = (i < CAP) ? sA[i] : part[e0 + i];
        int ln = (pk >> 17) & 255;
        int sv = pk & SRCMASK;
        int pos = atomicAdd(&posL[ln], 1);
        int idx = locL[ln] + pos;
        if (idx < CAP) sB[idx] = sv;
        else entries[e0 + idx] = sv;
    }
    __syncthreads();
    int lim = min(cnt, CAP);
    for (int i = t; i < lim; i += 256)
        entries[e0 + i] = sB[i];
}

// ---------------- MFMA GEMM: out16[r] = fp16( dis[r] * (h[r] @ W) ) ----------------
template <typename TIN>
__global__ __launch_bounds__(256) void gemm_mfma_k(const TIN* __restrict__ h,
                                                   const float* __restrict__ W,
                                                   const float* __restrict__ dis,
                                                   _Float16* __restrict__ out16) {
    __shared__ _Float16 wT[64 * 76];
    __shared__ _Float16 oS[64 * 64];
    int t = threadIdx.x;
    int wave = t >> 6, lane = t & 63;
    int m0 = blockIdx.x * 64 + wave * 16;
    int arow = min(m0 + (lane & 15), NN - 1);
    int kg = lane >> 4;

    f16x8 a0, a1;
    if constexpr (std::is_same<TIN, float>::value) {
        const float4* p0 = (const float4*)&h[(size_t)arow * 64 + kg * 8];
        const float4* p1 = (const float4*)&h[(size_t)arow * 64 + 32 + kg * 8];
        float4 x0 = p0[0], x1 = p0[1], y0 = p1[0], y1 = p1[1];
        a0[0] = (_Float16)x0.x; a0[1] = (_Float16)x0.y; a0[2] = (_Float16)x0.z; a0[3] = (_Float16)x0.w;
        a0[4] = (_Float16)x1.x; a0[5] = (_Float16)x1.y; a0[6] = (_Float16)x1.z; a0[7] = (_Float16)x1.w;
        a1[0] = (_Float16)y0.x; a1[1] = (_Float16)y0.y; a1[2] = (_Float16)y0.z; a1[3] = (_Float16)y0.w;
        a1[4] = (_Float16)y1.x; a1[5] = (_Float16)y1.y; a1[6] = (_Float16)y1.z; a1[7] = (_Float16)y1.w;
    } else {
        a0 = *(const f16x8*)&h[(size_t)arow * 64 + kg * 8];
        a1 = *(const f16x8*)&h[(size_t)arow * 64 + 32 + kg * 8];
    }

    for (int i = t; i < 4096; i += 256) {
        int k = i >> 6, c = i & 63;
        wT[c * 76 + k] = (_Float16)W[i];
    }
    __syncthreads();

    f32x4 acc[4];
#pragma unroll
    for (int i = 0; i < 4; i++) acc[i] = (f32x4){0.f, 0.f, 0.f, 0.f};

#pragma unroll
    for (int c0 = 0; c0 < 4; c0++) {
        const _Float16* wp = &wT[(c0 * 16 + (lane & 15)) * 76 + kg * 8];
        f16x8 b0 = *(const f16x8*)wp;
        f16x8 b1 = *(const f16x8*)(wp + 32);
        acc[c0] = __builtin_amdgcn_mfma_f32_16x16x32_f16(a0, b0, acc[c0], 0, 0, 0);
        acc[c0] = __builtin_amdgcn_mfma_f32_16x16x32_f16(a1, b1, acc[c0], 0, 0, 0);
    }

#pragma unroll
    for (int j = 0; j < 4; j++) {
        int row = (lane >> 4) * 4 + j;
        float dsc = dis[min(m0 + row, NN - 1)];
#pragma unroll
        for (int c0 = 0; c0 < 4; c0++)
            oS[(wave * 16 + row) * 64 + c0 * 16 + (lane & 15)] = (_Float16)(acc[c0][j] * dsc);
    }
    __syncthreads();

    int rbase = blockIdx.x * 64;
    for (int i = t; i < 512; i += 256) {
        int r = i >> 3;
        if (rbase + r < NN)
            ((int4*)&out16[(size_t)(rbase + r) * 64])[i & 7] = ((int4*)oS)[i];
    }
}

// ---------------- gather: 8B/lane, 4 rows per load instruction, zero-row padding ----------------
template <int LAST>
__global__ void gather_k(const _Float16* __restrict__ h2p, const int* __restrict__ rowptr,
                         const int* __restrict__ entries, const float* __restrict__ dis,
                         const float* __restrict__ bias, _Float16* __restrict__ out16,
                         float* __restrict__ outf) {
    int n = (blockIdx.x * blockDim.x + threadIdx.x) >> 6;
    if (n >= NN) return;
    int lane = threadIdx.x & 63;
    int q = lane >> 4;             // edge slot 0..3
    int fq = (lane & 15) * 4;      // feature quad

    int e0 = rowptr[n], e1 = rowptr[n + 1];

    // self term: only slot-0 lanes load the real row, others hit the zero row
    int sself = (q == 0) ? n : ZR;
    f16x4 sv = *(const f16x4*)&h2p[(size_t)sself * 64 + fq];
    float ax = (float)sv[0], ay = (float)sv[1], az = (float)sv[2], aw = (float)sv[3];

    for (int base = e0; base < e1; base += 64) {
        // lanes beyond the row's edge count hold the zero row -> unconditional loads
        int ent = (base + lane < e1) ? entries[base + lane] : ZR;
        int m = min(64, e1 - base);
        int iters = (m + 15) >> 4;                    // 1..4
        for (int it = 0; it < iters; ++it) {
            int d = it * 16;
            int s0 = __shfl(ent, d + q);
            int s1 = __shfl(ent, d + 4 + q);
            int s2 = __shfl(ent, d + 8 + q);
            int s3 = __shfl(ent, d + 12 + q);
            f16x4 v0 = *(const f16x4*)&h2p[(size_t)s0 * 64 + fq];
            f16x4 v1 = *(const f16x4*)&h2p[(size_t)s1 * 64 + fq];
            f16x4 v2 = *(const f16x4*)&h2p[(size_t)s2 * 64 + fq];
            f16x4 v3 = *(const f16x4*)&h2p[(size_t)s3 * 64 + fq];
            ax += ((float)v0[0] + (float)v1[0]) + ((float)v2[0] + (float)v3[0]);
            ay += ((float)v0[1] + (float)v1[1]) + ((float)v2[1] + (float)v3[1]);
            az += ((float)v0[2] + (float)v1[2]) + ((float)v2[2] + (float)v3[2]);
            aw += ((float)v0[3] + (float)v1[3]) + ((float)v2[3] + (float)v3[3]);
        }
    }
    // reduce the 4 edge slots
    ax += __shfl_xor(ax, 16); ay += __shfl_xor(ay, 16);
    az += __shfl_xor(az, 16); aw += __shfl_xor(aw, 16);
    ax += __shfl_xor(ax, 32); ay += __shfl_xor(ay, 32);
    az += __shfl_xor(az, 32); aw += __shfl_xor(aw, 32);

    if (lane < 16) {
        float dn = dis[n];
        float4 bv = *(const float4*)&bias[fq];
        float rx = bv.x + dn * ax;
        float ry = bv.y + dn * ay;
        float rz = bv.z + dn * az;
        float rw = bv.w + dn * aw;
        if (LAST) {
            float4 o = make_float4(rx, ry, rz, rw);
            *(float4*)&outf[(size_t)n * 64 + fq] = o;
        } else {
            f16x4 o;
            o[0] = (_Float16)fmaxf(rx, 0.f);
            o[1] = (_Float16)fmaxf(ry, 0.f);
            o[2] = (_Float16)fmaxf(rz, 0.f);
            o[3] = (_Float16)fmaxf(rw, 0.f);
            *(f16x4*)&out16[(size_t)n * 64 + fq] = o;
        }
    }
}

// ---------------- pooling ----------------
__global__ void pool_acc_k(const float* __restrict__ h, const int* __restrict__ batch,
                           float* __restrict__ pool) {
    int wid = (blockIdx.x * blockDim.x + threadIdx.x) >> 6;
    int lane = threadIdx.x & 63;
    int n0 = wid * 32;
    if (n0 >= NN) return;
    int n1 = min(n0 + 32, NN);
    int g = batch[n0];
    float acc = 0.0f;
    for (int n = n0; n < n1; n++) {
        int gn = batch[n];
        if (gn != g) {
            atomicAdd(&pool[g * FD + lane], acc);
            acc = 0.0f;
            g = gn;
        }
        acc += h[(size_t)n * FD + lane];
    }
    atomicAdd(&pool[g * FD + lane], acc);
}

__global__ void cnt_k(const int* __restrict__ batch, float* __restrict__ cnt) {
    int g = threadIdx.x;
    if (g >= NG) return;
    auto lb = [&](int key) {
        int lo = 0, hi = NN;
        while (lo < hi) {
            int mid = (lo + hi) >> 1;
            if (batch[mid] < key) lo = mid + 1; else hi = mid;
        }
        return lo;
    };
    cnt[g] = (float)(lb(g + 1) - lb(g));
}

__global__ void final_k(const float* __restrict__ pool, const float* __restrict__ cnt,
                        const float* __restrict__ lin_w, const float* __restrict__ lin_b,
                        float* __restrict__ out) {
    int g = blockIdx.x * blockDim.x + threadIdx.x;
    if (g >= NG) return;
    float c = fmaxf(cnt[g], 1.0f);
    float s = 0.0f;
    for (int f = 0; f < FD; f++) s += pool[g * FD + f] * lin_w[f];
    out[g] = s / c + lin_b[0];
}

extern "C" void kernel_launch(void* const* d_in, const int* in_sizes, int n_in,
                              void* d_out, int out_size, void* d_ws, size_t ws_size,
                              hipStream_t stream) {
    const float* x     = (const float*)d_in[0];
    const int*   src   = (const int*)d_in[1];
    const int*   dst   = ((const int*)d_in[1]) + NE;
    const int*   batch = (const int*)d_in[2];
    const float* W1 = (const float*)d_in[3];  const float* b1 = (const float*)d_in[4];
    const float* W2 = (const float*)d_in[5];  const float* b2 = (const float*)d_in[6];
    const float* W3 = (const float*)d_in[7];  const float* b3 = (const float*)d_in[8];
    const float* W4 = (const float*)d_in[9];  const float* b4 = (const float*)d_in[10];
    const float* lin_w = (const float*)d_in[11];
    const float* lin_b = (const float*)d_in[12];
    float* out = (float*)d_out;

    // workspace layout (part overlays aggf: part dead before gather4 writes aggf)
    char* p = (char*)d_ws;
    float*    aggf    = (float*)p;                 // NN*FD fp32 (25.6MB)
    int*      part    = (int*)p;      p += (size_t)NN * FD * 4;   // packed edges (6.4MB, overlaid)
    _Float16* h16a    = (_Float16*)p; p += (size_t)NN * FD * 2;          // gather out / gemm in
    _Float16* h16b    = (_Float16*)p; p += (size_t)(NN + 1) * FD * 2;    // gemm out (+zero row)
    int*      entries = (int*)p;      p += (size_t)NE * 4;
    float*    dis     = (float*)p;    p += (size_t)NN * 4;
    int*      rowptr  = (int*)p;      p += (size_t)(NN + 4) * 4;
    int*      bhist   = (int*)p;      p += ((NB + 3) & ~3) * 4;
    int*      bbase   = (int*)p;      p += ((NB + 4) & ~3) * 4;
    int*      gcursor = (int*)p;      p += ((NB + 3) & ~3) * 4;
    float*    pool    = (float*)p;    p += (size_t)NG * FD * 4;
    float*    cnt     = (float*)p;    p += (size_t)NG * 4;

    const int EGRID = (NE + 4095) / 4096;   // 391

    // ---- CSR build ----
    hipMemsetAsync(bhist, 0, NB * 4, stream);
    hipMemsetAsync(h16b + (size_t)ZR * FD, 0, FD * 2, stream);   // zero row
    bhist_k<<<EGRID, 256, 0, stream>>>(dst, bhist);
    bscan_k<<<1, 512, 0, stream>>>(bhist, bbase, gcursor);
    part1_k<<<EGRID, 256, 0, stream>>>(src, dst, gcursor, part);
    csr2_k<<<NB, 256, 0, stream>>>(part, bbase, rowptr, dis, entries);

    const int GEMM_GRID = (NN + 63) / 64;
    const int WAVE_GRID = ((size_t)NN * 64 + 255) / 256;

    gemm_mfma_k<float><<<GEMM_GRID, 256, 0, stream>>>(x, W1, dis, h16b);
    gather_k<0><<<WAVE_GRID, 256, 0, stream>>>(h16b, rowptr, entries, dis, b1, h16a, nullptr);
    gemm_mfma_k<_Float16><<<GEMM_GRID, 256, 0, stream>>>(h16a, W2, dis, h16b);
    gather_k<0><<<WAVE_GRID, 256, 0, stream>>>(h16b, rowptr, entries, dis, b2, h16a, nullptr);
    gemm_mfma_k<_Float16><<<GEMM_GRID, 256, 0, stream>>>(h16a, W3, dis, h16b);
    gather_k<0><<<WAVE_GRID, 256, 0, stream>>>(h16b, rowptr, entries, dis, b3, h16a, nullptr);
    gemm_mfma_k<_Float16><<<GEMM_GRID, 256, 0, stream>>>(h16a, W4, dis, h16b);
    gather_k<1><<<WAVE_GRID, 256, 0, stream>>>(h16b, rowptr, entries, dis, b4, nullptr, aggf);

    // ---- pooling + final ----
    hipMemsetAsync(pool, 0, (size_t)NG * FD * 4, stream);
    pool_acc_k<<<((NN + 31) / 32 * 64 + 255) / 256, 256, 0, stream>>>(aggf, batch, pool);
    cnt_k<<<1, 128, 0, stream>>>(batch, cnt);
    final_k<<<1, 128, 0, stream>>>(pool, cnt, lin_w, lin_b, out);
}